// Round 18
// baseline (491.953 us; speedup 1.0000x reference)
//
#include <hip/hip_runtime.h>

using u16 = unsigned short;
using u32 = unsigned int;

typedef float  f32x4  __attribute__((ext_vector_type(4)));
typedef float  f32x16 __attribute__((ext_vector_type(16)));
typedef u32    u32x4  __attribute__((ext_vector_type(4)));
typedef _Float16 f16;
typedef f16 f16x8 __attribute__((ext_vector_type(8)));

#define DEVI static __device__ __forceinline__

constexpr int S_  = 2048;
constexpr int D_  = 1024;
constexpr int HD_ = 64;
constexpr int SH_ = S_*HD_;
constexpr size_t NE_ = 8192ull*1024ull;

DEVI f32x4 mfma16f(f16x8 a, f16x8 b, f32x4 c){
  return __builtin_amdgcn_mfma_f32_16x16x32_f16(a, b, c, 0, 0, 0);
}
DEVI f32x16 mfma32(f16x8 a, f16x8 b, f32x16 c){
  return __builtin_amdgcn_mfma_f32_32x32x16_f16(a, b, c, 0, 0, 0);
}
DEVI float exp2fast(float x){
#if __has_builtin(__builtin_amdgcn_exp2f)
  return __builtin_amdgcn_exp2f(x);
#else
  float r; asm("v_exp_f32 %0, %1" : "=v"(r) : "v"(x)); return r;
#endif
}
DEVI float rcpfast(float x){
#if __has_builtin(__builtin_amdgcn_rcpf)
  return __builtin_amdgcn_rcpf(x);
#else
  float r; asm("v_rcp_f32 %0, %1" : "=v"(r) : "v"(x)); return r;
#endif
}
DEVI u32 pkh(float a, float b){
  return __builtin_bit_cast(u32, __builtin_amdgcn_cvt_pkrtz(a, b));
}
DEVI void gld16(const void* g, void* l){
  __builtin_amdgcn_global_load_lds(
      (const __attribute__((address_space(1))) u32*)g,
      (__attribute__((address_space(3))) u32*)l, 16, 0, 0);
}
DEVI void gld4(const void* g, void* l){
  __builtin_amdgcn_global_load_lds(
      (const __attribute__((address_space(1))) u32*)g,
      (__attribute__((address_space(3))) u32*)l, 4, 0, 0);
}

// ---------------- weight transpose: W[k][n] f32 -> Wt[n][k] f16 ----------------
__global__ __launch_bounds__(256) void wcvt_k(
    const float* __restrict__ wq, const float* __restrict__ wk,
    const float* __restrict__ wv, const float* __restrict__ wo,
    u16* __restrict__ wt)
{
  int z = blockIdx.z;
  const float* W = (z==0)?wq:(z==1)?wk:(z==2)?wv:wo;
  u16* ot = wt + (size_t)z*D_*D_;
  __shared__ float t[64][65];
  int k0 = blockIdx.y*64, n0 = blockIdx.x*64;
  int tid = threadIdx.x;
#pragma unroll
  for (int i=0;i<4;i++){
    int lin = i*256 + tid;
    int r = lin>>4, c = (lin&15)*4;
    f32x4 v = *reinterpret_cast<const f32x4*>(W + (size_t)(k0+r)*D_ + n0 + c);
    t[r][c+0]=v.x; t[r][c+1]=v.y; t[r][c+2]=v.z; t[r][c+3]=v.w;
  }
  __syncthreads();
  int n = tid>>2, c0 = (tid&3)*16;
  alignas(16) u16 hb[16];
#pragma unroll
  for (int i=0;i<16;i++) hb[i] = __builtin_bit_cast(u16, (f16)t[c0+i][n]);
  size_t off = (size_t)(n0+n)*D_ + k0 + c0;
  *reinterpret_cast<u32x4*>(ot+off)   = *reinterpret_cast<u32x4*>(hb);
  *reinterpret_cast<u32x4*>(ot+off+8) = *reinterpret_cast<u32x4*>(hb+8);
}

// ---------------- madd2 = (1-mask) * (-1e9 * log2e) ----------------
__global__ __launch_bounds__(256) void madd_k(const float* __restrict__ mask,
                                              float* __restrict__ madd2)
{
  int i = blockIdx.x*256 + threadIdx.x;
  if (i < 4*S_) madd2[i] = (1.0f - mask[i]) * -1442695040.0f;
}

// ---------------- fp16 GEMM: C = A @ Wt^T + bias, then *scale ----------------
// 256x128 tile, 512 threads (8 waves 4x2), BK=32, 3 LDS bufs, rotation swizzle.
// AF32: A f32 reg-staged with TWO named reg sets (depth-2), counted vmcnt.
// !AF32: A f16 via gld16 (3-deep).
struct GemmArgs {
  const void* A[3];
  const u16*  Wt[3];
  const float* bias[3];
  float*      outF[3];
  u16*        outH[3];
  float       scale[3];
  int         mode[3];
};

template<bool AF32>
__global__ __launch_bounds__(512, 4) void gemm_k(GemmArgs args)
{
  int z = blockIdx.z;
  const float* __restrict__ Af   = (const float*)args.A[z];
  const u16*   __restrict__ Ah   = (const u16*)args.A[z];
  const u16*   __restrict__ Wt   = args.Wt[z];
  const float* __restrict__ bias = args.bias[z];
  int mode = args.mode[z];
  float sc = args.scale[z];

  constexpr int ABYT = 16384;            // 256x32 f16
  constexpr int BUFS = ABYT + 8192;      // + 128x32 f16 = 24576
  __shared__ __align__(16) unsigned char smem[73728];
  char* sbase = (char*)smem;

  int m0 = blockIdx.x*256, n0 = blockIdx.y*128;
  int tid = threadIdx.x, lane = tid&63, w = tid>>6;      // w 0..7
  int wm = (w>>1)*64, wn = (w&1)*64;
  int lr = lane&15, lh = lane>>4;

  int offA[2], offB;
#pragma unroll
  for (int j=0;j<2;j++){
    int chunk = w*2 + j;
    int row = chunk*16 + (lane>>2);
    int gs = lane&3;
    offA[j] = row*D_ + (((gs - (row>>1)) & 3)*8);
  }
  {
    int row = w*16 + (lane>>2);
    int gs = lane&3;
    offB = row*D_ + (((gs - (row>>1)) & 3)*8);
  }

  int arow = w*32 + (lane>>1);
  const float* Abase = AF32 ? (Af + (size_t)(m0 + arow)*D_ + (lane&1)*16)
                            : (const float*)nullptr;

  f32x4 acc[4][4];
#pragma unroll
  for (int m=0;m<4;m++)
#pragma unroll
    for (int n=0;n<4;n++) acc[m][n] = f32x4{0.f,0.f,0.f,0.f};

  auto BSTAGE = [&](int kt){
    char* lB = sbase + (kt - (kt/3)*3)*BUFS + ABYT;
    gld16(Wt + (size_t)n0*D_ + kt*32 + offB, lB + w*1024);
  };
  auto ASTAGE16 = [&](int kt){
    char* lA = sbase + (kt - (kt/3)*3)*BUFS;
    const u16* As = Ah + (size_t)m0*D_ + kt*32;
#pragma unroll
    for (int j=0;j<2;j++) gld16(As + offA[j], lA + (w*2+j)*1024);
  };

  // TWO named staging sets (A(k) -> set k&1); no arrays, no pointers.
  f32x4 s0a, s0b, s0c, s0d;
  f32x4 s1a, s1b, s1c, s1d;

#define AISSUE0(kt) { \
  s0a = *reinterpret_cast<const f32x4*>(Abase + (kt)*32 + 0); \
  s0b = *reinterpret_cast<const f32x4*>(Abase + (kt)*32 + 4); \
  s0c = *reinterpret_cast<const f32x4*>(Abase + (kt)*32 + 8); \
  s0d = *reinterpret_cast<const f32x4*>(Abase + (kt)*32 + 12); }
#define AISSUE1(kt) { \
  s1a = *reinterpret_cast<const f32x4*>(Abase + (kt)*32 + 0); \
  s1b = *reinterpret_cast<const f32x4*>(Abase + (kt)*32 + 4); \
  s1c = *reinterpret_cast<const f32x4*>(Abase + (kt)*32 + 8); \
  s1d = *reinterpret_cast<const f32x4*>(Abase + (kt)*32 + 12); }

#define CONVERT_GEN(pa,pb,pc,pd,bufA) { \
  u32x4 w0_, w1_; \
  w0_.x = pkh(pa.x,pa.y); w0_.y = pkh(pa.z,pa.w); \
  w0_.z = pkh(pb.x,pb.y); w0_.w = pkh(pb.z,pb.w); \
  w1_.x = pkh(pc.x,pc.y); w1_.y = pkh(pc.z,pc.w); \
  w1_.z = pkh(pd.x,pd.y); w1_.w = pkh(pd.z,pd.w); \
  char* dst_ = (bufA) + arow*64; \
  int g0_ = (lane&1)*2; \
  *reinterpret_cast<u32x4*>(dst_ + (((g0_   + (arow>>1))&3)<<4)) = w0_; \
  *reinterpret_cast<u32x4*>(dst_ + (((g0_+1 + (arow>>1))&3)<<4)) = w1_; }
#define CONVERT0(bufA) CONVERT_GEN(s0a,s0b,s0c,s0d,bufA)
#define CONVERT1(bufA) CONVERT_GEN(s1a,s1b,s1c,s1d,bufA)

// one pipeline iteration body; CVT: 0 -> use set0, 1 -> use set1 for A(t+1)
#define AF32_BODY(t, CVTSET) { \
  int buf_ = (t) - ((t)/3)*3; \
  char* bA_ = sbase + buf_*BUFS; \
  char* bB_ = bA_ + ABYT; \
  if ((t) < 30)      asm volatile("s_waitcnt vmcnt(10)" ::: "memory"); \
  else if ((t)==30)  asm volatile("s_waitcnt vmcnt(5)"  ::: "memory"); \
  else               asm volatile("s_waitcnt vmcnt(0)"  ::: "memory"); \
  asm volatile("s_waitcnt lgkmcnt(0)" ::: "memory"); \
  __builtin_amdgcn_s_barrier(); \
  __builtin_amdgcn_sched_barrier(0); \
  f16x8 af_[4], bf_[4]; \
  _Pragma("unroll") \
  for (int m=0;m<4;m++){ \
    int row = wm + m*16 + lr; \
    af_[m] = *reinterpret_cast<const f16x8*>(bA_ + row*64 + (((lh + (row>>1)) & 3)<<4)); \
  } \
  _Pragma("unroll") \
  for (int n=0;n<4;n++){ \
    int row = wn + n*16 + lr; \
    bf_[n] = *reinterpret_cast<const f16x8*>(bB_ + row*64 + (((lh + (row>>1)) & 3)<<4)); \
  } \
  asm volatile("s_waitcnt lgkmcnt(0)" ::: "memory"); \
  __builtin_amdgcn_sched_barrier(0); \
  __builtin_amdgcn_s_barrier(); \
  if ((t) < 31){ \
    int nb_ = ((t)+1) - (((t)+1)/3)*3; \
    if constexpr (CVTSET == 0) { CONVERT0(sbase + nb_*BUFS); } \
    else                       { CONVERT1(sbase + nb_*BUFS); } \
  } \
  if ((t) < 29){ \
    if constexpr (CVTSET == 0) { AISSUE0((t)+3); } \
    else                       { AISSUE1((t)+3); } \
    BSTAGE((t)+3); \
  } \
  __builtin_amdgcn_s_setprio(1); \
  _Pragma("unroll") \
  for (int m=0;m<4;m++) \
    _Pragma("unroll") \
    for (int n=0;n<4;n++) \
      acc[m][n] = mfma16f(af_[m], bf_[n], acc[m][n]); \
  __builtin_amdgcn_s_setprio(0); }

  if constexpr (AF32){
    BSTAGE(0); BSTAGE(1); BSTAGE(2);
    AISSUE0(0);
    CONVERT0(sbase);       // waits A0 (drains B0-B2 too); writes buf0
    AISSUE1(1);            // A1 -> set1
    AISSUE0(2);            // A2 -> set0

    for (int i=0; i<16; ++i){
      int u = 2*i, v = 2*i + 1;
      AF32_BODY(u, 1);     // converts A(u+1) (odd -> set1), reissues set1
      AF32_BODY(v, 0);     // converts A(v+1) (even -> set0), reissues set0
    }
  } else {
    ASTAGE16(0); BSTAGE(0);
    ASTAGE16(1); BSTAGE(1);
    ASTAGE16(2); BSTAGE(2);

    for (int t=0; t<32; ++t){
      int buf = t - (t/3)*3;
      if (t < 30)       asm volatile("s_waitcnt vmcnt(6)" ::: "memory");
      else if (t == 30) asm volatile("s_waitcnt vmcnt(3)" ::: "memory");
      else              asm volatile("s_waitcnt vmcnt(0)" ::: "memory");
      __builtin_amdgcn_s_barrier();

      char* bA = sbase + buf*BUFS;
      char* bB = bA + ABYT;
      f16x8 af[4], bfr[4];
#pragma unroll
      for (int m=0;m<4;m++){
        int row = wm + m*16 + lr;
        af[m] = *reinterpret_cast<const f16x8*>(bA + row*64 + (((lh + (row>>1)) & 3)<<4));
      }
#pragma unroll
      for (int n=0;n<4;n++){
        int row = wn + n*16 + lr;
        bfr[n] = *reinterpret_cast<const f16x8*>(bB + row*64 + (((lh + (row>>1)) & 3)<<4));
      }
      asm volatile("s_waitcnt lgkmcnt(0)" ::: "memory");
      __builtin_amdgcn_sched_barrier(0);
      __builtin_amdgcn_s_barrier();
      if (t < 29){ ASTAGE16(t+3); BSTAGE(t+3); }

      __builtin_amdgcn_s_setprio(1);
#pragma unroll
      for (int m=0;m<4;m++)
#pragma unroll
        for (int n=0;n<4;n++)
          acc[m][n] = mfma16f(af[m], bfr[n], acc[m][n]);
      __builtin_amdgcn_s_setprio(0);
    }
  }
#undef AF32_BODY
#undef CONVERT0
#undef CONVERT1
#undef CONVERT_GEN
#undef AISSUE0
#undef AISSUE1

  float bsetv[4];
#pragma unroll
  for (int n=0;n<4;n++) bsetv[n] = bias[n0 + wn + n*16 + lr];

  if (mode == 0){
    float* out = args.outF[z];
#pragma unroll
    for (int m=0;m<4;m++)
#pragma unroll
      for (int n=0;n<4;n++)
#pragma unroll
        for (int r=0;r<4;r++){
          int row = m0 + wm + m*16 + lh*4 + r;
          int col = n0 + wn + n*16 + lr;
          out[(size_t)row*D_ + col] = (acc[m][n][r] + bsetv[n])*sc;
        }
  } else if (mode == 1){
    u16* oh = args.outH[z];
#pragma unroll
    for (int m=0;m<4;m++)
#pragma unroll
      for (int n=0;n<4;n++)
#pragma unroll
        for (int r=0;r<4;r++){
          int row = m0 + wm + m*16 + lh*4 + r;
          int col = n0 + wn + n*16 + lr;
          float val = (acc[m][n][r] + bsetv[n])*sc;
          int b = row >> 11, s = row & 2047;
          int hh = col >> 6,  dd = col & 63;
          oh[(size_t)(b*16 + hh)*SH_ + (size_t)s*HD_ + dd] =
              __builtin_bit_cast(u16, (f16)val);
        }
  } else {
    __syncthreads();
    u16* ct = (u16*)sbase;   // [256][132] f16 bits = 67584 B
#pragma unroll
    for (int m=0;m<4;m++)
#pragma unroll
      for (int n=0;n<4;n++)
#pragma unroll
        for (int r=0;r<4;r++){
          int lrow = wm + m*16 + lh*4 + r;
          int lcol = wn + n*16 + lr;
          ct[lrow*132 + lcol] = __builtin_bit_cast(u16, (f16)((acc[m][n][r] + bsetv[n])*sc));
        }
    __syncthreads();
    u16* ovt = args.outH[z];
    int b = m0 >> 11, s0 = m0 & 2047;
    int ch = tid >> 2, quarter = tid & 3;
    int gn = n0 + ch;
    int hh = gn >> 6, dd = gn & 63;
    size_t obase = (size_t)(b*16 + hh)*SH_ + (size_t)dd*S_ + s0 + quarter*64;
#pragma unroll
    for (int i=0;i<8;i++){
      alignas(16) u16 tmp[8];
#pragma unroll
      for (int j=0;j<8;j++) tmp[j] = ct[(quarter*64 + i*8 + j)*132 + ch];
      *reinterpret_cast<u32x4*>(ovt + obase + i*8) = *reinterpret_cast<u32x4*>(tmp);
    }
  }
}

// ---------------- flash attention, swapped 32x32 fp16, KVBLK=128 -------------
__global__ __launch_bounds__(256, 2) void attn_k(
    const f16* __restrict__ Qf, const f16* __restrict__ Kf,
    const f16* __restrict__ Vt, const float* __restrict__ madd2,
    u16* __restrict__ cf)
{
  constexpr int BUFS = 33280;   // 16K K + 16K V + 512 M
  __shared__ __align__(16) unsigned char smem[2*BUFS];
  char* sbase = (char*)smem;

  int flat = blockIdx.x + blockIdx.y*gridDim.x;  // 0..1023
  int xcd = flat & 7, ix = flat >> 3;
  int bh = xcd + 8*(ix >> 4);
  int qx = ix & 15;
  int b = bh >> 4, head = bh & 15;

  const f16* Qb = Qf + (size_t)bh*SH_;
  const f16* Kb = Kf + (size_t)bh*SH_;
  const f16* Vb = Vt + (size_t)bh*SH_;
  const float* mb = madd2 + (size_t)b*S_;

  int tid = threadIdx.x, lane = tid&63, w = tid>>6;
  int q31 = lane&31, h = lane>>5;
  int qw = qx*128 + w*32;
  int xorv = (q31&7)<<4;

  f16x8 qb[4];
#pragma unroll
  for (int ks=0;ks<4;ks++)
    qb[ks] = *reinterpret_cast<const f16x8*>(Qb + (size_t)(qw + q31)*HD_ + ks*16 + h*8);

  int offK[4], offV[4];
#pragma unroll
  for (int j=0;j<4;j++){
    int L = (w*4+j)*1024 + lane*16;
    int rK = L>>7;
    int dbyK = (L&127) ^ ((rK&7)<<4);
    offK[j] = rK*HD_ + (dbyK>>1);
    int rV = L>>8;
    int dbyV = (L&255) ^ ((rV&7)<<4);
    offV[j] = rV*S_ + (dbyV>>1);
  }

  u32 one2 = 0x3C003C00u;
  u32x4 onev; onev.x=one2; onev.y=one2; onev.z=one2; onev.w=one2;
  f16x8 vones = __builtin_bit_cast(f16x8, onev);

  f32x16 z16;
#pragma unroll
  for (int r=0;r<16;r++) z16[r] = 0.f;

  f32x16 o[2], ol;
#pragma unroll
  for (int n=0;n<2;n++)
#pragma unroll
    for (int r=0;r<16;r++) o[n][r] = 0.f;
#pragma unroll
  for (int r=0;r<16;r++) ol[r] = 0.f;

  auto STAGE = [&](int buf, int t){
    int kv0 = t*128;
    char* sKb = sbase + buf*BUFS;
    char* sVb = sKb + 16384;
    char* sMb = sKb + 32768;
#pragma unroll
    for (int j=0;j<4;j++)
      gld16(Kb + (size_t)kv0*HD_ + offK[j], sKb + (w*4+j)*1024);
#pragma unroll
    for (int j=0;j<4;j++)
      gld16(Vb + kv0 + offV[j], sVb + (w*4+j)*1024);
    gld4(mb + kv0 + lane, sMb);
    gld4(mb + kv0 + 64 + lane, sMb + 256);
  };

  STAGE(0, 0);
  STAGE(1, 1);

  for (int t=0; t<16; ++t){
    int buf = t&1;
    char* sKb = sbase + buf*BUFS;
    char* sVb = sKb + 16384;
    float* sMb = (float*)(sKb + 32768);

    if (t < 15) asm volatile("s_waitcnt vmcnt(10)" ::: "memory");
    else        asm volatile("s_waitcnt vmcnt(0)"  ::: "memory");
    __builtin_amdgcn_s_barrier();
    __builtin_amdgcn_sched_barrier(0);

    f32x16 stA[2], stB[2];

    __builtin_amdgcn_s_setprio(1);
#pragma unroll
    for (int n=0;n<2;n++){
      int rb = (n*32 + q31)*128;
      f16x8 ka = *reinterpret_cast<const f16x8*>(sKb + ((rb + h*16) ^ xorv));
      stA[n] = mfma32(ka, qb[0], z16);
#pragma unroll
      for (int ks=1;ks<4;ks++){
        ka = *reinterpret_cast<const f16x8*>(sKb + ((rb + ks*32 + h*16) ^ xorv));
        stA[n] = mfma32(ka, qb[ks], stA[n]);
      }
    }
#pragma unroll
    for (int n=0;n<2;n++){
      int rb = (64 + n*32 + q31)*128;
      f16x8 ka = *reinterpret_cast<const f16x8*>(sKb + ((rb + h*16) ^ xorv));
      stB[n] = mfma32(ka, qb[0], z16);
#pragma unroll
      for (int ks=1;ks<4;ks++){
        ka = *reinterpret_cast<const f16x8*>(sKb + ((rb + ks*32 + h*16) ^ xorv));
        stB[n] = mfma32(ka, qb[ks], stB[n]);
      }
    }
    __builtin_amdgcn_s_setprio(0);

    auto SMPV = [&](int sub, f32x16 (&st)[2]){
      float mval = sMb[sub*64 + lane];
      if (__ballot(mval != 0.0f)){
#pragma unroll
        for (int n=0;n<2;n++)
#pragma unroll
          for (int g=0;g<4;g++){
            f32x4 mv = *reinterpret_cast<const f32x4*>(sMb + sub*64 + n*32 + g*8 + h*4);
#pragma unroll
            for (int c=0;c<4;c++) st[n][g*4+c] += mv[c];
          }
      }
#pragma unroll
      for (int n=0;n<2;n++)
#pragma unroll
        for (int r=0;r<16;r++) st[n][r] = exp2fast(st[n][r]);

      f16x8 pa[4];
#pragma unroll
      for (int n=0;n<2;n++){
        u32 x[4], y[4];
#pragma unroll
        for (int T=0;T<4;T++){
          x[T] = pkh(st[n][4*T+0], st[n][4*T+1]);
          y[T] = pkh(st[n][4*T+2], st[n][4*T+3]);
        }
#pragma unroll
        for (int k2=0;k2<2;k2++){
          u32 a0=x[2*k2], b0=x[2*k2+1], a1=y[2*k2], b1=y[2*k2+1];
          asm volatile("v_permlane32_swap_b32 %0, %1" : "+v"(a0), "+v"(b0));
          asm volatile("v_permlane32_swap_b32 %0, %1" : "+v"(a1), "+v"(b1));
          u32x4 wv;
          wv.x = a0;
          wv.y = a1;
          wv.z = b0;
          wv.w = b1;
          pa[2*n+k2] = __builtin_bit_cast(f16x8, wv);
        }
      }

      __builtin_amdgcn_s_setprio(1);
#pragma unroll
      for (int n=0;n<2;n++){
        int rbv = (n*32 + q31)*256 + sub*128;
#pragma unroll
        for (int ks=0;ks<4;ks++){
          f16x8 vbf = *reinterpret_cast<const f16x8*>(sVb + ((rbv + ks*32 + h*16) ^ xorv));
          o[n] = mfma32(pa[ks], vbf, o[n]);
        }
      }
#pragma unroll
      for (int ks=0;ks<4;ks++)
        ol = mfma32(pa[ks], vones, ol);
      __builtin_amdgcn_s_setprio(0);
    };

    SMPV(0, stA);
    SMPV(1, stB);

    asm volatile("s_waitcnt lgkmcnt(0)" ::: "memory");
    __builtin_amdgcn_s_barrier();
    __builtin_amdgcn_sched_barrier(0);
    if (t < 14) STAGE(buf, t+2);
  }

#pragma unroll
  for (int n=0;n<2;n++)
#pragma unroll
    for (int r=0;r<16;r++){
      float inv = rcpfast(ol[r]);
      int s = qw + (r&3) + 8*(r>>2) + 4*h;
      int d = head*HD_ + n*32 + q31;
      cf[((size_t)(b*S_ + s))*D_ + d] = __builtin_bit_cast(u16, (f16)(o[n][r]*inv));
    }
}

extern "C" void kernel_launch(void* const* d_in, const int* in_sizes, int n_in,
                              void* d_out, int out_size, void* d_ws, size_t ws_size,
                              hipStream_t stream)
{
  (void)in_sizes; (void)n_in; (void)out_size;
  const float* query=(const float*)d_in[0];
  const float* key  =(const float*)d_in[1];
  const float* value=(const float*)d_in[2];
  const float* mask =(const float*)d_in[3];
  const float* wq=(const float*)d_in[4];
  const float* bq=(const float*)d_in[5];
  const float* wk=(const float*)d_in[6];
  const float* bk=(const float*)d_in[7];
  const float* wv=(const float*)d_in[8];
  const float* bv=(const float*)d_in[9];
  const float* wo=(const float*)d_in[10];
  const float* bo=(const float*)d_in[11];
  float* out = (float*)d_out;

  const size_t WN = 4ull*1024*1024;
  size_t need = WN*2 + 4*NE_*2 + 8192*4;
  if (ws_size < need) return;

  char* ws = (char*)d_ws;
  u16* wt = (u16*)ws;
  u16* qf = wt + WN;
  u16* kf = qf + NE_;
  u16* vt = kf + NE_;
  u16* cf = vt + NE_;
  float* madd2 = (float*)(cf + NE_);

  const float CSC = 0.18033688011112042f;  // 0.125 * log2(e)

  wcvt_k<<<dim3(16,16,4), 256, 0, stream>>>(wq,wk,wv,wo,wt);
  madd_k<<<dim3(32), 256, 0, stream>>>(mask, madd2);

  GemmArgs ga{};
  ga.A[0]=query; ga.A[1]=key; ga.A[2]=value;
  ga.Wt[0]=wt;           ga.Wt[1]=wt+1048576;   ga.Wt[2]=wt+2097152;
  ga.bias[0]=bq; ga.bias[1]=bk; ga.bias[2]=bv;
  ga.scale[0]=CSC; ga.scale[1]=1.0f; ga.scale[2]=1.0f;
  ga.mode[0]=1;  ga.mode[1]=1;  ga.mode[2]=2;
  ga.outH[0]=qf; ga.outH[1]=kf; ga.outH[2]=vt;
  gemm_k<true><<<dim3(32,8,3), 512, 0, stream>>>(ga);

  attn_k<<<dim3(16,64), 256, 0, stream>>>((const f16*)qf,(const f16*)kf,(const f16*)vt,madd2,cf);

  GemmArgs go{};
  go.A[0]=cf;
  go.Wt[0]=wt+3145728;
  go.bias[0]=bo; go.scale[0]=1.0f; go.mode[0]=0; go.outF[0]=out;
  gemm_k<false><<<dim3(32,8,1), 512, 0, stream>>>(go);
}

// Round 19
// 196.917 us; speedup vs baseline: 2.4983x; 2.4983x over previous
//
#include <hip/hip_runtime.h>

using u16 = unsigned short;
using u32 = unsigned int;

typedef float  f32x4  __attribute__((ext_vector_type(4)));
typedef float  f32x16 __attribute__((ext_vector_type(16)));
typedef u32    u32x4  __attribute__((ext_vector_type(4)));
typedef _Float16 f16;
typedef f16 f16x8 __attribute__((ext_vector_type(8)));

#define DEVI static __device__ __forceinline__

constexpr int S_  = 2048;
constexpr int D_  = 1024;
constexpr int HD_ = 64;
constexpr int SH_ = S_*HD_;
constexpr size_t NE_ = 8192ull*1024ull;

DEVI f32x4 mfma16f(f16x8 a, f16x8 b, f32x4 c){
  return __builtin_amdgcn_mfma_f32_16x16x32_f16(a, b, c, 0, 0, 0);
}
DEVI f32x16 mfma32(f16x8 a, f16x8 b, f32x16 c){
  return __builtin_amdgcn_mfma_f32_32x32x16_f16(a, b, c, 0, 0, 0);
}
DEVI float exp2fast(float x){
#if __has_builtin(__builtin_amdgcn_exp2f)
  return __builtin_amdgcn_exp2f(x);
#else
  float r; asm("v_exp_f32 %0, %1" : "=v"(r) : "v"(x)); return r;
#endif
}
DEVI float rcpfast(float x){
#if __has_builtin(__builtin_amdgcn_rcpf)
  return __builtin_amdgcn_rcpf(x);
#else
  float r; asm("v_rcp_f32 %0, %1" : "=v"(r) : "v"(x)); return r;
#endif
}
DEVI u32 pkh(float a, float b){
  return __builtin_bit_cast(u32, __builtin_amdgcn_cvt_pkrtz(a, b));
}
DEVI void gld16(const void* g, void* l){
  __builtin_amdgcn_global_load_lds(
      (const __attribute__((address_space(1))) u32*)g,
      (__attribute__((address_space(3))) u32*)l, 16, 0, 0);
}
DEVI void gld4(const void* g, void* l){
  __builtin_amdgcn_global_load_lds(
      (const __attribute__((address_space(1))) u32*)g,
      (__attribute__((address_space(3))) u32*)l, 4, 0, 0);
}

// ------- weight transpose W[k][n] f32 -> Wt[n][k] f16; z==4: madd2 -------
__global__ __launch_bounds__(256) void wcvt_k(
    const float* __restrict__ wq, const float* __restrict__ wk,
    const float* __restrict__ wv, const float* __restrict__ wo,
    u16* __restrict__ wt, const float* __restrict__ mask,
    float* __restrict__ madd2)
{
  int z = blockIdx.z;
  if (z == 4){
    int i = (blockIdx.y*16 + blockIdx.x)*256 + threadIdx.x;
    if (i < 4*S_) madd2[i] = (1.0f - mask[i]) * -1442695040.0f;
    return;
  }
  const float* W = (z==0)?wq:(z==1)?wk:(z==2)?wv:wo;
  u16* ot = wt + (size_t)z*D_*D_;
  __shared__ float t[64][65];
  int k0 = blockIdx.y*64, n0 = blockIdx.x*64;
  int tid = threadIdx.x;
#pragma unroll
  for (int i=0;i<4;i++){
    int lin = i*256 + tid;
    int r = lin>>4, c = (lin&15)*4;
    f32x4 v = *reinterpret_cast<const f32x4*>(W + (size_t)(k0+r)*D_ + n0 + c);
    t[r][c+0]=v.x; t[r][c+1]=v.y; t[r][c+2]=v.z; t[r][c+3]=v.w;
  }
  __syncthreads();
  int n = tid>>2, c0 = (tid&3)*16;
  alignas(16) u16 hb[16];
#pragma unroll
  for (int i=0;i<16;i++) hb[i] = __builtin_bit_cast(u16, (f16)t[c0+i][n]);
  size_t off = (size_t)(n0+n)*D_ + k0 + c0;
  *reinterpret_cast<u32x4*>(ot+off)   = *reinterpret_cast<u32x4*>(hb);
  *reinterpret_cast<u32x4*>(ot+off+8) = *reinterpret_cast<u32x4*>(hb+8);
}

// ---------------- fp16 GEMM: C = A @ Wt^T + bias, then *scale ----------------
// 256x128 tile, 512 threads (8 waves 4x2), BK=32.
// AF32: A f32 staged via global_load_lds (XOR swizzle), cvt after ds_read;
// 2-buffer counted-vmcnt pipeline. !AF32: A f16, 3-buffer rotation swizzle.
struct GemmArgs {
  const void* A[3];
  const u16*  Wt[3];
  const float* bias[3];
  float*      outF[3];
  u16*        outH[3];
  float       scale[3];
  int         mode[3];
};

template<bool AF32>
__global__ __launch_bounds__(512, 4) void gemm_k(GemmArgs args)
{
  int z = blockIdx.z;
  const float* __restrict__ Af   = (const float*)args.A[z];
  const u16*   __restrict__ Ah   = (const u16*)args.A[z];
  const u16*   __restrict__ Wt   = args.Wt[z];
  const float* __restrict__ bias = args.bias[z];
  int mode = args.mode[z];
  float sc = args.scale[z];

  constexpr int ABYT = AF32 ? 32768 : 16384;
  constexpr int BUFS = ABYT + 8192;
  constexpr int NBUF = AF32 ? 2 : 3;
  __shared__ __align__(16) unsigned char smem[AF32 ? 81920 : 73728];
  char* sbase = (char*)smem;

  int m0 = blockIdx.x*256, n0 = blockIdx.y*128;
  int tid = threadIdx.x, lane = tid&63, w = tid>>6;      // w 0..7
  int wm = (w>>1)*64, wn = (w&1)*64;
  int lr = lane&15, lh = lane>>4;

  int offA[4], offB;
  if constexpr (AF32){
#pragma unroll
    for (int j=0;j<4;j++){
      int chunk = w*4 + j;                 // 1024B chunk = 8 f32-rows
      int row = chunk*8 + (lane>>3);
      int g = lane&7;
      offA[j] = row*D_ + ((g ^ (row&7))*4);   // f32 elements
    }
  } else {
#pragma unroll
    for (int j=0;j<2;j++){
      int chunk = w*2 + j;                 // 1024B chunk = 16 f16-rows
      int row = chunk*16 + (lane>>2);
      int gs = lane&3;
      offA[j] = row*D_ + (((gs - (row>>1)) & 3)*8);  // f16 elements
    }
  }
  {
    int row = w*16 + (lane>>2);
    int gs = lane&3;
    offB = row*D_ + (((gs - (row>>1)) & 3)*8);
  }

  f32x4 acc[4][4];
#pragma unroll
  for (int m=0;m<4;m++)
#pragma unroll
    for (int n=0;n<4;n++) acc[m][n] = f32x4{0.f,0.f,0.f,0.f};

  auto STAGE = [&](int buf, int kt){
    char* lA = sbase + buf*BUFS;
    char* lB = lA + ABYT;
    if constexpr (AF32){
      const float* As = Af + (size_t)m0*D_ + kt*32;
#pragma unroll
      for (int j=0;j<4;j++) gld16(As + offA[j], lA + (w*4+j)*1024);
    } else {
      const u16* As = Ah + (size_t)m0*D_ + kt*32;
#pragma unroll
      for (int j=0;j<2;j++) gld16(As + offA[j], lA + (w*2+j)*1024);
    }
    const u16* Bs = Wt + (size_t)n0*D_ + kt*32;
    gld16(Bs + offB, lB + w*1024);
  };

  STAGE(0, 0);
  STAGE(1, 1);
  if constexpr (!AF32) STAGE(2, 2);

  for (int kt=0; kt<32; ++kt){
    int buf = kt - (kt/NBUF)*NBUF;
    if constexpr (AF32){
      if (kt < 31) asm volatile("s_waitcnt vmcnt(5)" ::: "memory");
      else         asm volatile("s_waitcnt vmcnt(0)" ::: "memory");
    } else {
      if (kt < 30)       asm volatile("s_waitcnt vmcnt(6)" ::: "memory");
      else if (kt == 30) asm volatile("s_waitcnt vmcnt(3)" ::: "memory");
      else               asm volatile("s_waitcnt vmcnt(0)" ::: "memory");
    }
    __builtin_amdgcn_s_barrier();

    char* bA = sbase + buf*BUFS;
    char* bB = bA + ABYT;
    f16x8 af[4], bfr[4];
#pragma unroll
    for (int m=0;m<4;m++){
      int row = wm + m*16 + lr;
      if constexpr (AF32){
        f32x4 a0 = *reinterpret_cast<const f32x4*>(bA + row*128 + ((((lh<<1)  ) ^ (row&7))<<4));
        f32x4 a1 = *reinterpret_cast<const f32x4*>(bA + row*128 + ((((lh<<1)|1) ^ (row&7))<<4));
        u32x4 uw;
        uw.x = pkh(a0.x,a0.y); uw.y = pkh(a0.z,a0.w);
        uw.z = pkh(a1.x,a1.y); uw.w = pkh(a1.z,a1.w);
        af[m] = __builtin_bit_cast(f16x8, uw);
      } else {
        af[m] = *reinterpret_cast<const f16x8*>(bA + row*64 + (((lh + (row>>1)) & 3)<<4));
      }
    }
#pragma unroll
    for (int n=0;n<4;n++){
      int row = wn + n*16 + lr;
      bfr[n] = *reinterpret_cast<const f16x8*>(bB + row*64 + (((lh + (row>>1)) & 3)<<4));
    }
    asm volatile("s_waitcnt lgkmcnt(0)" ::: "memory");
    __builtin_amdgcn_sched_barrier(0);
    __builtin_amdgcn_s_barrier();
    if constexpr (AF32){
      if (kt < 30) STAGE(buf, kt+2);
    } else {
      if (kt < 29) STAGE(buf, kt+3);
    }

    __builtin_amdgcn_s_setprio(1);
#pragma unroll
    for (int m=0;m<4;m++)
#pragma unroll
      for (int n=0;n<4;n++)
        acc[m][n] = mfma16f(af[m], bfr[n], acc[m][n]);
    __builtin_amdgcn_s_setprio(0);
  }

  float bsetv[4];
#pragma unroll
  for (int n=0;n<4;n++) bsetv[n] = bias[n0 + wn + n*16 + lr];

  if (mode == 0){
    float* out = args.outF[z];
#pragma unroll
    for (int m=0;m<4;m++)
#pragma unroll
      for (int n=0;n<4;n++)
#pragma unroll
        for (int r=0;r<4;r++){
          int row = m0 + wm + m*16 + lh*4 + r;
          int col = n0 + wn + n*16 + lr;
          out[(size_t)row*D_ + col] = (acc[m][n][r] + bsetv[n])*sc;
        }
  } else if (mode == 1){
    u16* oh = args.outH[z];
#pragma unroll
    for (int m=0;m<4;m++)
#pragma unroll
      for (int n=0;n<4;n++)
#pragma unroll
        for (int r=0;r<4;r++){
          int row = m0 + wm + m*16 + lh*4 + r;
          int col = n0 + wn + n*16 + lr;
          float val = (acc[m][n][r] + bsetv[n])*sc;
          int b = row >> 11, s = row & 2047;
          int hh = col >> 6,  dd = col & 63;
          oh[(size_t)(b*16 + hh)*SH_ + (size_t)s*HD_ + dd] =
              __builtin_bit_cast(u16, (f16)val);
        }
  } else {
    __syncthreads();
    u16* ct = (u16*)sbase;   // [256][132] f16 bits = 67584 B
#pragma unroll
    for (int m=0;m<4;m++)
#pragma unroll
      for (int n=0;n<4;n++)
#pragma unroll
        for (int r=0;r<4;r++){
          int lrow = wm + m*16 + lh*4 + r;
          int lcol = wn + n*16 + lr;
          ct[lrow*132 + lcol] = __builtin_bit_cast(u16, (f16)((acc[m][n][r] + bsetv[n])*sc));
        }
    __syncthreads();
    u16* ovt = args.outH[z];
    int b = m0 >> 11, s0 = m0 & 2047;
    int ch = tid >> 2, quarter = tid & 3;
    int gn = n0 + ch;
    int hh = gn >> 6, dd = gn & 63;
    size_t obase = (size_t)(b*16 + hh)*SH_ + (size_t)dd*S_ + s0 + quarter*64;
#pragma unroll
    for (int i=0;i<8;i++){
      alignas(16) u16 tmp[8];
#pragma unroll
      for (int j=0;j<8;j++) tmp[j] = ct[(quarter*64 + i*8 + j)*132 + ch];
      *reinterpret_cast<u32x4*>(ovt + obase + i*8) = *reinterpret_cast<u32x4*>(tmp);
    }
  }
}

// ---------------- flash attention, swapped 32x32 fp16, KVBLK=128 -------------
__global__ __launch_bounds__(256, 2) void attn_k(
    const f16* __restrict__ Qf, const f16* __restrict__ Kf,
    const f16* __restrict__ Vt, const float* __restrict__ madd2,
    u16* __restrict__ cf)
{
  constexpr int BUFS = 33280;   // 16K K + 16K V + 512 M
  __shared__ __align__(16) unsigned char smem[2*BUFS];
  char* sbase = (char*)smem;

  int flat = blockIdx.x + blockIdx.y*gridDim.x;  // 0..1023
  int xcd = flat & 7, ix = flat >> 3;
  int bh = xcd + 8*(ix >> 4);
  int qx = ix & 15;
  int b = bh >> 4, head = bh & 15;

  const f16* Qb = Qf + (size_t)bh*SH_;
  const f16* Kb = Kf + (size_t)bh*SH_;
  const f16* Vb = Vt + (size_t)bh*SH_;
  const float* mb = madd2 + (size_t)b*S_;

  int tid = threadIdx.x, lane = tid&63, w = tid>>6;
  int q31 = lane&31, h = lane>>5;
  int qw = qx*128 + w*32;
  int xorv = (q31&7)<<4;

  f16x8 qb[4];
#pragma unroll
  for (int ks=0;ks<4;ks++)
    qb[ks] = *reinterpret_cast<const f16x8*>(Qb + (size_t)(qw + q31)*HD_ + ks*16 + h*8);

  int offK[4], offV[4];
#pragma unroll
  for (int j=0;j<4;j++){
    int L = (w*4+j)*1024 + lane*16;
    int rK = L>>7;
    int dbyK = (L&127) ^ ((rK&7)<<4);
    offK[j] = rK*HD_ + (dbyK>>1);
    int rV = L>>8;
    int dbyV = (L&255) ^ ((rV&7)<<4);
    offV[j] = rV*S_ + (dbyV>>1);
  }

  u32 one2 = 0x3C003C00u;
  u32x4 onev; onev.x=one2; onev.y=one2; onev.z=one2; onev.w=one2;
  f16x8 vones = __builtin_bit_cast(f16x8, onev);

  f32x16 z16;
#pragma unroll
  for (int r=0;r<16;r++) z16[r] = 0.f;

  f32x16 o[2], ol;
#pragma unroll
  for (int n=0;n<2;n++)
#pragma unroll
    for (int r=0;r<16;r++) o[n][r] = 0.f;
#pragma unroll
  for (int r=0;r<16;r++) ol[r] = 0.f;

  auto STAGE = [&](int buf, int t){
    int kv0 = t*128;
    char* sKb = sbase + buf*BUFS;
    char* sVb = sKb + 16384;
    char* sMb = sKb + 32768;
#pragma unroll
    for (int j=0;j<4;j++)
      gld16(Kb + (size_t)kv0*HD_ + offK[j], sKb + (w*4+j)*1024);
#pragma unroll
    for (int j=0;j<4;j++)
      gld16(Vb + kv0 + offV[j], sVb + (w*4+j)*1024);
    gld4(mb + kv0 + lane, sMb);
    gld4(mb + kv0 + 64 + lane, sMb + 256);
  };

  STAGE(0, 0);
  STAGE(1, 1);

  for (int t=0; t<16; ++t){
    int buf = t&1;
    char* sKb = sbase + buf*BUFS;
    char* sVb = sKb + 16384;
    float* sMb = (float*)(sKb + 32768);

    if (t < 15) asm volatile("s_waitcnt vmcnt(10)" ::: "memory");
    else        asm volatile("s_waitcnt vmcnt(0)"  ::: "memory");
    __builtin_amdgcn_s_barrier();
    __builtin_amdgcn_sched_barrier(0);

    f32x16 stA[2], stB[2];

    __builtin_amdgcn_s_setprio(1);
#pragma unroll
    for (int n=0;n<2;n++){
      int rb = (n*32 + q31)*128;
      f16x8 ka = *reinterpret_cast<const f16x8*>(sKb + ((rb + h*16) ^ xorv));
      stA[n] = mfma32(ka, qb[0], z16);
#pragma unroll
      for (int ks=1;ks<4;ks++){
        ka = *reinterpret_cast<const f16x8*>(sKb + ((rb + ks*32 + h*16) ^ xorv));
        stA[n] = mfma32(ka, qb[ks], stA[n]);
      }
    }
#pragma unroll
    for (int n=0;n<2;n++){
      int rb = (64 + n*32 + q31)*128;
      f16x8 ka = *reinterpret_cast<const f16x8*>(sKb + ((rb + h*16) ^ xorv));
      stB[n] = mfma32(ka, qb[0], z16);
#pragma unroll
      for (int ks=1;ks<4;ks++){
        ka = *reinterpret_cast<const f16x8*>(sKb + ((rb + ks*32 + h*16) ^ xorv));
        stB[n] = mfma32(ka, qb[ks], stB[n]);
      }
    }
    __builtin_amdgcn_s_setprio(0);

    auto SMPV = [&](int sub, f32x16 (&st)[2]){
      float mval = sMb[sub*64 + lane];
      if (__ballot(mval != 0.0f)){
#pragma unroll
        for (int n=0;n<2;n++)
#pragma unroll
          for (int g=0;g<4;g++){
            f32x4 mv = *reinterpret_cast<const f32x4*>(sMb + sub*64 + n*32 + g*8 + h*4);
#pragma unroll
            for (int c=0;c<4;c++) st[n][g*4+c] += mv[c];
          }
      }
#pragma unroll
      for (int n=0;n<2;n++)
#pragma unroll
        for (int r=0;r<16;r++) st[n][r] = exp2fast(st[n][r]);

      f16x8 pa[4];
#pragma unroll
      for (int n=0;n<2;n++){
        u32 x[4], y[4];
#pragma unroll
        for (int T=0;T<4;T++){
          x[T] = pkh(st[n][4*T+0], st[n][4*T+1]);
          y[T] = pkh(st[n][4*T+2], st[n][4*T+3]);
        }
#pragma unroll
        for (int k2=0;k2<2;k2++){
          u32 a0=x[2*k2], b0=x[2*k2+1], a1=y[2*k2], b1=y[2*k2+1];
          asm volatile("v_permlane32_swap_b32 %0, %1" : "+v"(a0), "+v"(b0));
          asm volatile("v_permlane32_swap_b32 %0, %1" : "+v"(a1), "+v"(b1));
          u32x4 wv;
          wv.x = a0;
          wv.y = a1;
          wv.z = b0;
          wv.w = b1;
          pa[2*n+k2] = __builtin_bit_cast(f16x8, wv);
        }
      }

      __builtin_amdgcn_s_setprio(1);
#pragma unroll
      for (int n=0;n<2;n++){
        int rbv = (n*32 + q31)*256 + sub*128;
#pragma unroll
        for (int ks=0;ks<4;ks++){
          f16x8 vbf = *reinterpret_cast<const f16x8*>(sVb + ((rbv + ks*32 + h*16) ^ xorv));
          o[n] = mfma32(pa[ks], vbf, o[n]);
        }
      }
#pragma unroll
      for (int ks=0;ks<4;ks++)
        ol = mfma32(pa[ks], vones, ol);
      __builtin_amdgcn_s_setprio(0);
    };

    SMPV(0, stA);
    SMPV(1, stB);

    asm volatile("s_waitcnt lgkmcnt(0)" ::: "memory");
    __builtin_amdgcn_s_barrier();
    __builtin_amdgcn_sched_barrier(0);
    if (t < 14) STAGE(buf, t+2);
  }

#pragma unroll
  for (int n=0;n<2;n++)
#pragma unroll
    for (int r=0;r<16;r++){
      float inv = rcpfast(ol[r]);
      int s = qw + (r&3) + 8*(r>>2) + 4*h;
      int d = head*HD_ + n*32 + q31;
      cf[((size_t)(b*S_ + s))*D_ + d] = __builtin_bit_cast(u16, (f16)(o[n][r]*inv));
    }
}

extern "C" void kernel_launch(void* const* d_in, const int* in_sizes, int n_in,
                              void* d_out, int out_size, void* d_ws, size_t ws_size,
                              hipStream_t stream)
{
  (void)in_sizes; (void)n_in; (void)out_size;
  const float* query=(const float*)d_in[0];
  const float* key  =(const float*)d_in[1];
  const float* value=(const float*)d_in[2];
  const float* mask =(const float*)d_in[3];
  const float* wq=(const float*)d_in[4];
  const float* bq=(const float*)d_in[5];
  const float* wk=(const float*)d_in[6];
  const float* bk=(const float*)d_in[7];
  const float* wv=(const float*)d_in[8];
  const float* bv=(const float*)d_in[9];
  const float* wo=(const float*)d_in[10];
  const float* bo=(const float*)d_in[11];
  float* out = (float*)d_out;

  const size_t WN = 4ull*1024*1024;
  size_t need = WN*2 + 4*NE_*2 + 8192*4;
  if (ws_size < need) return;

  char* ws = (char*)d_ws;
  u16* wt = (u16*)ws;
  u16* qf = wt + WN;
  u16* kf = qf + NE_;
  u16* vt = kf + NE_;
  u16* cf = vt + NE_;
  float* madd2 = (float*)(cf + NE_);

  const float CSC = 0.18033688011112042f;  // 0.125 * log2(e)

  wcvt_k<<<dim3(16,16,5), 256, 0, stream>>>(wq,wk,wv,wo,wt,mask,madd2);

  GemmArgs ga{};
  ga.A[0]=query; ga.A[1]=key; ga.A[2]=value;
  ga.Wt[0]=wt;           ga.Wt[1]=wt+1048576;   ga.Wt[2]=wt+2097152;
  ga.bias[0]=bq; ga.bias[1]=bk; ga.bias[2]=bv;
  ga.scale[0]=CSC; ga.scale[1]=1.0f; ga.scale[2]=1.0f;
  ga.mode[0]=1;  ga.mode[1]=1;  ga.mode[2]=2;
  ga.outH[0]=qf; ga.outH[1]=kf; ga.outH[2]=vt;
  gemm_k<true><<<dim3(32,8,3), 512, 0, stream>>>(ga);

  attn_k<<<dim3(16,64), 256, 0, stream>>>((const f16*)qf,(const f16*)kf,(const f16*)vt,madd2,cf);

  GemmArgs go{};
  go.A[0]=cf;
  go.Wt[0]=wt+3145728;
  go.bias[0]=bo; go.scale[0]=1.0f; go.mode[0]=0; go.outF[0]=out;
  gemm_k<false><<<dim3(32,8,1), 512, 0, stream>>>(go);
}

// Round 20
// 196.254 us; speedup vs baseline: 2.5067x; 1.0034x over previous
//
#include <hip/hip_runtime.h>

using u16 = unsigned short;
using u32 = unsigned int;

typedef float  f32x4  __attribute__((ext_vector_type(4)));
typedef float  f32x16 __attribute__((ext_vector_type(16)));
typedef u32    u32x4  __attribute__((ext_vector_type(4)));
typedef _Float16 f16;
typedef f16 f16x8 __attribute__((ext_vector_type(8)));

#define DEVI static __device__ __forceinline__

constexpr int S_  = 2048;
constexpr int D_  = 1024;
constexpr int HD_ = 64;
constexpr int SH_ = S_*HD_;
constexpr size_t NE_ = 8192ull*1024ull;

DEVI f32x4 mfma16f(f16x8 a, f16x8 b, f32x4 c){
  return __builtin_amdgcn_mfma_f32_16x16x32_f16(a, b, c, 0, 0, 0);
}
DEVI f32x16 mfma32(f16x8 a, f16x8 b, f32x16 c){
  return __builtin_amdgcn_mfma_f32_32x32x16_f16(a, b, c, 0, 0, 0);
}
DEVI float exp2fast(float x){
#if __has_builtin(__builtin_amdgcn_exp2f)
  return __builtin_amdgcn_exp2f(x);
#else
  float r; asm("v_exp_f32 %0, %1" : "=v"(r) : "v"(x)); return r;
#endif
}
DEVI float rcpfast(float x){
#if __has_builtin(__builtin_amdgcn_rcpf)
  return __builtin_amdgcn_rcpf(x);
#else
  float r; asm("v_rcp_f32 %0, %1" : "=v"(r) : "v"(x)); return r;
#endif
}
DEVI u32 pkh(float a, float b){
  return __builtin_bit_cast(u32, __builtin_amdgcn_cvt_pkrtz(a, b));
}
DEVI void gld16(const void* g, void* l){
  __builtin_amdgcn_global_load_lds(
      (const __attribute__((address_space(1))) u32*)g,
      (__attribute__((address_space(3))) u32*)l, 16, 0, 0);
}
DEVI void gld4(const void* g, void* l){
  __builtin_amdgcn_global_load_lds(
      (const __attribute__((address_space(1))) u32*)g,
      (__attribute__((address_space(3))) u32*)l, 4, 0, 0);
}

// ------- weight transpose W[k][n] f32 -> Wt[n][k] f16; z==4: madd2 -------
__global__ __launch_bounds__(256) void wcvt_k(
    const float* __restrict__ wq, const float* __restrict__ wk,
    const float* __restrict__ wv, const float* __restrict__ wo,
    u16* __restrict__ wt, const float* __restrict__ mask,
    float* __restrict__ madd2)
{
  int z = blockIdx.z;
  if (z == 4){
    int i = (blockIdx.y*16 + blockIdx.x)*256 + threadIdx.x;
    if (i < 4*S_) madd2[i] = (1.0f - mask[i]) * -1442695040.0f;
    return;
  }
  const float* W = (z==0)?wq:(z==1)?wk:(z==2)?wv:wo;
  u16* ot = wt + (size_t)z*D_*D_;
  __shared__ float t[64][65];
  int k0 = blockIdx.y*64, n0 = blockIdx.x*64;
  int tid = threadIdx.x;
#pragma unroll
  for (int i=0;i<4;i++){
    int lin = i*256 + tid;
    int r = lin>>4, c = (lin&15)*4;
    f32x4 v = *reinterpret_cast<const f32x4*>(W + (size_t)(k0+r)*D_ + n0 + c);
    t[r][c+0]=v.x; t[r][c+1]=v.y; t[r][c+2]=v.z; t[r][c+3]=v.w;
  }
  __syncthreads();
  int n = tid>>2, c0 = (tid&3)*16;
  alignas(16) u16 hb[16];
#pragma unroll
  for (int i=0;i<16;i++) hb[i] = __builtin_bit_cast(u16, (f16)t[c0+i][n]);
  size_t off = (size_t)(n0+n)*D_ + k0 + c0;
  *reinterpret_cast<u32x4*>(ot+off)   = *reinterpret_cast<u32x4*>(hb);
  *reinterpret_cast<u32x4*>(ot+off+8) = *reinterpret_cast<u32x4*>(hb+8);
}

// ---------------- fp16 GEMM: C = A @ Wt^T + bias, then *scale ----------------
// 256x128 tile, 512 threads (8 waves 4x2), BK=32.
// AF32: A f32 staged via global_load_lds (XOR swizzle), cvt after ds_read;
// 2-buffer counted-vmcnt pipeline. !AF32: A f16, 3-buffer rotation swizzle.
struct GemmArgs {
  const void* A[3];
  const u16*  Wt[3];
  const float* bias[3];
  float*      outF[3];
  u16*        outH[3];
  float       scale[3];
  int         mode[3];
};

template<bool AF32>
__global__ __launch_bounds__(512, 4) void gemm_k(GemmArgs args)
{
  int z = blockIdx.z;
  const float* __restrict__ Af   = (const float*)args.A[z];
  const u16*   __restrict__ Ah   = (const u16*)args.A[z];
  const u16*   __restrict__ Wt   = args.Wt[z];
  const float* __restrict__ bias = args.bias[z];
  int mode = args.mode[z];
  float sc = args.scale[z];

  constexpr int ABYT = AF32 ? 32768 : 16384;
  constexpr int BUFS = ABYT + 8192;
  constexpr int NBUF = AF32 ? 2 : 3;
  __shared__ __align__(16) unsigned char smem[AF32 ? 81920 : 73728];
  char* sbase = (char*)smem;

  int m0 = blockIdx.x*256, n0 = blockIdx.y*128;
  int tid = threadIdx.x, lane = tid&63, w = tid>>6;      // w 0..7
  int wm = (w>>1)*64, wn = (w&1)*64;
  int lr = lane&15, lh = lane>>4;

  int offA[4], offB;
  if constexpr (AF32){
#pragma unroll
    for (int j=0;j<4;j++){
      int chunk = w*4 + j;                 // 1024B chunk = 8 f32-rows
      int row = chunk*8 + (lane>>3);
      int g = lane&7;
      offA[j] = row*D_ + ((g ^ (row&7))*4);   // f32 elements
    }
  } else {
#pragma unroll
    for (int j=0;j<2;j++){
      int chunk = w*2 + j;                 // 1024B chunk = 16 f16-rows
      int row = chunk*16 + (lane>>2);
      int gs = lane&3;
      offA[j] = row*D_ + (((gs - (row>>1)) & 3)*8);  // f16 elements
    }
  }
  {
    int row = w*16 + (lane>>2);
    int gs = lane&3;
    offB = row*D_ + (((gs - (row>>1)) & 3)*8);
  }

  f32x4 acc[4][4];
#pragma unroll
  for (int m=0;m<4;m++)
#pragma unroll
    for (int n=0;n<4;n++) acc[m][n] = f32x4{0.f,0.f,0.f,0.f};

  auto STAGE = [&](int buf, int kt){
    char* lA = sbase + buf*BUFS;
    char* lB = lA + ABYT;
    if constexpr (AF32){
      const float* As = Af + (size_t)m0*D_ + kt*32;
#pragma unroll
      for (int j=0;j<4;j++) gld16(As + offA[j], lA + (w*4+j)*1024);
    } else {
      const u16* As = Ah + (size_t)m0*D_ + kt*32;
#pragma unroll
      for (int j=0;j<2;j++) gld16(As + offA[j], lA + (w*2+j)*1024);
    }
    const u16* Bs = Wt + (size_t)n0*D_ + kt*32;
    gld16(Bs + offB, lB + w*1024);
  };

  STAGE(0, 0);
  STAGE(1, 1);
  if constexpr (!AF32) STAGE(2, 2);

  for (int kt=0; kt<32; ++kt){
    int buf = kt - (kt/NBUF)*NBUF;
    if constexpr (AF32){
      if (kt < 31) asm volatile("s_waitcnt vmcnt(5)" ::: "memory");
      else         asm volatile("s_waitcnt vmcnt(0)" ::: "memory");
    } else {
      if (kt < 30)       asm volatile("s_waitcnt vmcnt(6)" ::: "memory");
      else if (kt == 30) asm volatile("s_waitcnt vmcnt(3)" ::: "memory");
      else               asm volatile("s_waitcnt vmcnt(0)" ::: "memory");
    }
    __builtin_amdgcn_s_barrier();

    char* bA = sbase + buf*BUFS;
    char* bB = bA + ABYT;
    f16x8 af[4], bfr[4];
#pragma unroll
    for (int m=0;m<4;m++){
      int row = wm + m*16 + lr;
      if constexpr (AF32){
        f32x4 a0 = *reinterpret_cast<const f32x4*>(bA + row*128 + ((((lh<<1)  ) ^ (row&7))<<4));
        f32x4 a1 = *reinterpret_cast<const f32x4*>(bA + row*128 + ((((lh<<1)|1) ^ (row&7))<<4));
        u32x4 uw;
        uw.x = pkh(a0.x,a0.y); uw.y = pkh(a0.z,a0.w);
        uw.z = pkh(a1.x,a1.y); uw.w = pkh(a1.z,a1.w);
        af[m] = __builtin_bit_cast(f16x8, uw);
      } else {
        af[m] = *reinterpret_cast<const f16x8*>(bA + row*64 + (((lh + (row>>1)) & 3)<<4));
      }
    }
#pragma unroll
    for (int n=0;n<4;n++){
      int row = wn + n*16 + lr;
      bfr[n] = *reinterpret_cast<const f16x8*>(bB + row*64 + (((lh + (row>>1)) & 3)<<4));
    }
    asm volatile("s_waitcnt lgkmcnt(0)" ::: "memory");
    __builtin_amdgcn_sched_barrier(0);
    __builtin_amdgcn_s_barrier();
    if constexpr (AF32){
      if (kt < 30) STAGE(buf, kt+2);
    } else {
      if (kt < 29) STAGE(buf, kt+3);
    }

    __builtin_amdgcn_s_setprio(1);
#pragma unroll
    for (int m=0;m<4;m++)
#pragma unroll
      for (int n=0;n<4;n++)
        acc[m][n] = mfma16f(af[m], bfr[n], acc[m][n]);
    __builtin_amdgcn_s_setprio(0);
  }

  float bsetv[4];
#pragma unroll
  for (int n=0;n<4;n++) bsetv[n] = bias[n0 + wn + n*16 + lr];

  if (mode == 0){
    float* out = args.outF[z];
#pragma unroll
    for (int m=0;m<4;m++)
#pragma unroll
      for (int n=0;n<4;n++)
#pragma unroll
        for (int r=0;r<4;r++){
          int row = m0 + wm + m*16 + lh*4 + r;
          int col = n0 + wn + n*16 + lr;
          out[(size_t)row*D_ + col] = (acc[m][n][r] + bsetv[n])*sc;
        }
  } else if (mode == 1){
    u16* oh = args.outH[z];
#pragma unroll
    for (int m=0;m<4;m++)
#pragma unroll
      for (int n=0;n<4;n++)
#pragma unroll
        for (int r=0;r<4;r++){
          int row = m0 + wm + m*16 + lh*4 + r;
          int col = n0 + wn + n*16 + lr;
          float val = (acc[m][n][r] + bsetv[n])*sc;
          int b = row >> 11, s = row & 2047;
          int hh = col >> 6,  dd = col & 63;
          oh[(size_t)(b*16 + hh)*SH_ + (size_t)s*HD_ + dd] =
              __builtin_bit_cast(u16, (f16)val);
        }
  } else {
    __syncthreads();
    u16* ct = (u16*)sbase;   // [256][132] f16 bits = 67584 B
#pragma unroll
    for (int m=0;m<4;m++)
#pragma unroll
      for (int n=0;n<4;n++)
#pragma unroll
        for (int r=0;r<4;r++){
          int lrow = wm + m*16 + lh*4 + r;
          int lcol = wn + n*16 + lr;
          ct[lrow*132 + lcol] = __builtin_bit_cast(u16, (f16)((acc[m][n][r] + bsetv[n])*sc));
        }
    __syncthreads();
    u16* ovt = args.outH[z];
    int b = m0 >> 11, s0 = m0 & 2047;
    int ch = tid >> 2, quarter = tid & 3;
    int gn = n0 + ch;
    int hh = gn >> 6, dd = gn & 63;
    size_t obase = (size_t)(b*16 + hh)*SH_ + (size_t)dd*S_ + s0 + quarter*64;
#pragma unroll
    for (int i=0;i<8;i++){
      alignas(16) u16 tmp[8];
#pragma unroll
      for (int j=0;j<8;j++) tmp[j] = ct[(quarter*64 + i*8 + j)*132 + ch];
      *reinterpret_cast<u32x4*>(ovt + obase + i*8) = *reinterpret_cast<u32x4*>(tmp);
    }
  }
}

// ---------------- flash attention, swapped 32x32 fp16, KVBLK=128 -------------
// Mask staging only on wave 0 (wave-split counted vmcnt).
__global__ __launch_bounds__(256, 2) void attn_k(
    const f16* __restrict__ Qf, const f16* __restrict__ Kf,
    const f16* __restrict__ Vt, const float* __restrict__ madd2,
    u16* __restrict__ cf)
{
  constexpr int BUFS = 33280;   // 16K K + 16K V + 512 M
  __shared__ __align__(16) unsigned char smem[2*BUFS];
  char* sbase = (char*)smem;

  int flat = blockIdx.x + blockIdx.y*gridDim.x;  // 0..1023
  int xcd = flat & 7, ix = flat >> 3;
  int bh = xcd + 8*(ix >> 4);
  int qx = ix & 15;
  int b = bh >> 4, head = bh & 15;

  const f16* Qb = Qf + (size_t)bh*SH_;
  const f16* Kb = Kf + (size_t)bh*SH_;
  const f16* Vb = Vt + (size_t)bh*SH_;
  const float* mb = madd2 + (size_t)b*S_;

  int tid = threadIdx.x, lane = tid&63, w = tid>>6;
  int q31 = lane&31, h = lane>>5;
  int qw = qx*128 + w*32;
  int xorv = (q31&7)<<4;

  f16x8 qb[4];
#pragma unroll
  for (int ks=0;ks<4;ks++)
    qb[ks] = *reinterpret_cast<const f16x8*>(Qb + (size_t)(qw + q31)*HD_ + ks*16 + h*8);

  int offK[4], offV[4];
#pragma unroll
  for (int j=0;j<4;j++){
    int L = (w*4+j)*1024 + lane*16;
    int rK = L>>7;
    int dbyK = (L&127) ^ ((rK&7)<<4);
    offK[j] = rK*HD_ + (dbyK>>1);
    int rV = L>>8;
    int dbyV = (L&255) ^ ((rV&7)<<4);
    offV[j] = rV*S_ + (dbyV>>1);
  }

  u32 one2 = 0x3C003C00u;
  u32x4 onev; onev.x=one2; onev.y=one2; onev.z=one2; onev.w=one2;
  f16x8 vones = __builtin_bit_cast(f16x8, onev);

  f32x16 z16;
#pragma unroll
  for (int r=0;r<16;r++) z16[r] = 0.f;

  f32x16 o[2], ol;
#pragma unroll
  for (int n=0;n<2;n++)
#pragma unroll
    for (int r=0;r<16;r++) o[n][r] = 0.f;
#pragma unroll
  for (int r=0;r<16;r++) ol[r] = 0.f;

  auto STAGE = [&](int buf, int t){
    int kv0 = t*128;
    char* sKb = sbase + buf*BUFS;
    char* sVb = sKb + 16384;
    char* sMb = sKb + 32768;
#pragma unroll
    for (int j=0;j<4;j++)
      gld16(Kb + (size_t)kv0*HD_ + offK[j], sKb + (w*4+j)*1024);
#pragma unroll
    for (int j=0;j<4;j++)
      gld16(Vb + kv0 + offV[j], sVb + (w*4+j)*1024);
    if (w == 0){
      gld4(mb + kv0 + lane, sMb);
      gld4(mb + kv0 + 64 + lane, sMb + 256);
    }
  };

  STAGE(0, 0);
  STAGE(1, 1);

  for (int t=0; t<16; ++t){
    int buf = t&1;
    char* sKb = sbase + buf*BUFS;
    char* sVb = sKb + 16384;
    float* sMb = (float*)(sKb + 32768);

    if (t < 15){
      if (w == 0) asm volatile("s_waitcnt vmcnt(10)" ::: "memory");
      else        asm volatile("s_waitcnt vmcnt(8)"  ::: "memory");
    } else {
      asm volatile("s_waitcnt vmcnt(0)"  ::: "memory");
    }
    __builtin_amdgcn_s_barrier();
    __builtin_amdgcn_sched_barrier(0);

    f32x16 stA[2], stB[2];

    __builtin_amdgcn_s_setprio(1);
#pragma unroll
    for (int n=0;n<2;n++){
      int rb = (n*32 + q31)*128;
      f16x8 ka = *reinterpret_cast<const f16x8*>(sKb + ((rb + h*16) ^ xorv));
      stA[n] = mfma32(ka, qb[0], z16);
#pragma unroll
      for (int ks=1;ks<4;ks++){
        ka = *reinterpret_cast<const f16x8*>(sKb + ((rb + ks*32 + h*16) ^ xorv));
        stA[n] = mfma32(ka, qb[ks], stA[n]);
      }
    }
#pragma unroll
    for (int n=0;n<2;n++){
      int rb = (64 + n*32 + q31)*128;
      f16x8 ka = *reinterpret_cast<const f16x8*>(sKb + ((rb + h*16) ^ xorv));
      stB[n] = mfma32(ka, qb[0], z16);
#pragma unroll
      for (int ks=1;ks<4;ks++){
        ka = *reinterpret_cast<const f16x8*>(sKb + ((rb + ks*32 + h*16) ^ xorv));
        stB[n] = mfma32(ka, qb[ks], stB[n]);
      }
    }
    __builtin_amdgcn_s_setprio(0);

    auto SMPV = [&](int sub, f32x16 (&st)[2]){
      float mval = sMb[sub*64 + lane];
      if (__ballot(mval != 0.0f)){
#pragma unroll
        for (int n=0;n<2;n++)
#pragma unroll
          for (int g=0;g<4;g++){
            f32x4 mv = *reinterpret_cast<const f32x4*>(sMb + sub*64 + n*32 + g*8 + h*4);
#pragma unroll
            for (int c=0;c<4;c++) st[n][g*4+c] += mv[c];
          }
      }
#pragma unroll
      for (int n=0;n<2;n++)
#pragma unroll
        for (int r=0;r<16;r++) st[n][r] = exp2fast(st[n][r]);

      f16x8 pa[4];
#pragma unroll
      for (int n=0;n<2;n++){
        u32 x[4], y[4];
#pragma unroll
        for (int T=0;T<4;T++){
          x[T] = pkh(st[n][4*T+0], st[n][4*T+1]);
          y[T] = pkh(st[n][4*T+2], st[n][4*T+3]);
        }
#pragma unroll
        for (int k2=0;k2<2;k2++){
          u32 a0=x[2*k2], b0=x[2*k2+1], a1=y[2*k2], b1=y[2*k2+1];
          asm volatile("v_permlane32_swap_b32 %0, %1" : "+v"(a0), "+v"(b0));
          asm volatile("v_permlane32_swap_b32 %0, %1" : "+v"(a1), "+v"(b1));
          u32x4 wv;
          wv.x = a0;
          wv.y = a1;
          wv.z = b0;
          wv.w = b1;
          pa[2*n+k2] = __builtin_bit_cast(f16x8, wv);
        }
      }

      __builtin_amdgcn_s_setprio(1);
#pragma unroll
      for (int n=0;n<2;n++){
        int rbv = (n*32 + q31)*256 + sub*128;
#pragma unroll
        for (int ks=0;ks<4;ks++){
          f16x8 vbf = *reinterpret_cast<const f16x8*>(sVb + ((rbv + ks*32 + h*16) ^ xorv));
          o[n] = mfma32(pa[ks], vbf, o[n]);
        }
      }
#pragma unroll
      for (int ks=0;ks<4;ks++)
        ol = mfma32(pa[ks], vones, ol);
      __builtin_amdgcn_s_setprio(0);
    };

    SMPV(0, stA);
    SMPV(1, stB);

    asm volatile("s_waitcnt lgkmcnt(0)" ::: "memory");
    __builtin_amdgcn_s_barrier();
    __builtin_amdgcn_sched_barrier(0);
    if (t < 14) STAGE(buf, t+2);
  }

#pragma unroll
  for (int n=0;n<2;n++)
#pragma unroll
    for (int r=0;r<16;r++){
      float inv = rcpfast(ol[r]);
      int s = qw + (r&3) + 8*(r>>2) + 4*h;
      int d = head*HD_ + n*32 + q31;
      cf[((size_t)(b*S_ + s))*D_ + d] = __builtin_bit_cast(u16, (f16)(o[n][r]*inv));
    }
}

extern "C" void kernel_launch(void* const* d_in, const int* in_sizes, int n_in,
                              void* d_out, int out_size, void* d_ws, size_t ws_size,
                              hipStream_t stream)
{
  (void)in_sizes; (void)n_in; (void)out_size;
  const float* query=(const float*)d_in[0];
  const float* key  =(const float*)d_in[1];
  const float* value=(const float*)d_in[2];
  const float* mask =(const float*)d_in[3];
  const float* wq=(const float*)d_in[4];
  const float* bq=(const float*)d_in[5];
  const float* wk=(const float*)d_in[6];
  const float* bk=(const float*)d_in[7];
  const float* wv=(const float*)d_in[8];
  const float* bv=(const float*)d_in[9];
  const float* wo=(const float*)d_in[10];
  const float* bo=(const float*)d_in[11];
  float* out = (float*)d_out;

  const size_t WN = 4ull*1024*1024;
  size_t need = WN*2 + 4*NE_*2 + 8192*4;
  if (ws_size < need) return;

  char* ws = (char*)d_ws;
  u16* wt = (u16*)ws;
  u16* qf = wt + WN;
  u16* kf = qf + NE_;
  u16* vt = kf + NE_;
  u16* cf = vt + NE_;
  float* madd2 = (float*)(cf + NE_);

  const float CSC = 0.18033688011112042f;  // 0.125 * log2(e)

  wcvt_k<<<dim3(16,16,5), 256, 0, stream>>>(wq,wk,wv,wo,wt,mask,madd2);

  GemmArgs ga{};
  ga.A[0]=query; ga.A[1]=key; ga.A[2]=value;
  ga.Wt[0]=wt;           ga.Wt[1]=wt+1048576;   ga.Wt[2]=wt+2097152;
  ga.bias[0]=bq; ga.bias[1]=bk; ga.bias[2]=bv;
  ga.scale[0]=CSC; ga.scale[1]=1.0f; ga.scale[2]=1.0f;
  ga.mode[0]=1;  ga.mode[1]=1;  ga.mode[2]=2;
  ga.outH[0]=qf; ga.outH[1]=kf; ga.outH[2]=vt;
  gemm_k<true><<<dim3(32,8,3), 512, 0, stream>>>(ga);

  attn_k<<<dim3(16,64), 256, 0, stream>>>((const f16*)qf,(const f16*)kf,(const f16*)vt,madd2,cf);

  GemmArgs go{};
  go.A[0]=cf;
  go.Wt[0]=wt+3145728;
  go.bias[0]=bo; go.scale[0]=1.0f; go.mode[0]=0; go.outF[0]=out;
  gemm_k<false><<<dim3(32,8,1), 512, 0, stream>>>(go);
}